// Round 8
// baseline (244.251 us; speedup 1.0000x reference)
//
#include <hip/hip_runtime.h>
#include <math.h>

#define BB 32
#define CCH 224
#define TTT 2048
#define BT (BB*TTT)        // 65536
#define TPB 64             // t per kf tile
#define NT  (TTT/TPB)      // 32 tiles
#define CG  28             // channels per kf block
#define NCG (CCH/CG)       // 8  -> 256 blocks = 1 block/CU
#define IROW 29            // f64 per Is row (28 + 1 pad)
#define RD 4               // ring depth

// flag indices (generation counters, monotone)
#define PF(h,s) ((h)*RD+(s))    // conv wave h wrote Is slot s
#define CF(s)   (8+(s))         // scan consumed Is slot s
#define SF(s)   (12+(s))        // scan wrote bits slot s
#define OW(s)   (16+(s))        // out-writer consumed bits slot s

// LDS-only release: order prior DS ops before the flag store WITHOUT
// draining vmcnt (global prefetches stay in flight across handoffs).
#define LDS_REL() asm volatile("s_waitcnt lgkmcnt(0)" ::: "memory")
#define CFENCE()  asm volatile("" ::: "memory")

// ---------------------------------------------------------------------------
// kw: per (b,t): f64 dot over C -> w -> 7 symmetric Gaussian taps (f64, SoA).
// grid (8 t-chunks, 32 b) x 256. Wave w sums channels {w, w+4, ...} (56 each)
// reading CONTIGUOUS 1 KB per instruction (64 lanes x float4 along t).
// Tail (recurrence + 2 exps) on all 256 threads (one per t).
// ---------------------------------------------------------------------------
__global__ __launch_bounds__(256) void kw(
    const float* __restrict__ x, const float* __restrict__ lw,
    double* __restrict__ kernG)
{
    __shared__ double sd[4][256];
    __shared__ float  lws[CCH];
    const int b    = blockIdx.y;
    const int t0   = blockIdx.x << 8;     // 256-t chunk
    const int tid  = threadIdx.x;
    const int w    = tid >> 6, lane = tid & 63;

    if (tid < CCH) lws[tid] = lw[tid];
    __syncthreads();

    {   // phase 1: partial dot, fully-coalesced row-chunk loads
        const float* xb = x + (((size_t)(b * CCH + w)) << 11) + t0 + 4 * lane;
        double a0 = 0, a1 = 0, a2 = 0, a3 = 0;
        #pragma unroll 8
        for (int i = 0; i < 56; ++i) {
            float4 v = *(const float4*)(xb + ((size_t)(4 * i) << 11));
            double wv = (double)lws[w + 4 * i];
            a0 += (double)v.x * wv;
            a1 += (double)v.y * wv;
            a2 += (double)v.z * wv;
            a3 += (double)v.w * wv;
        }
        sd[w][4 * lane + 0] = a0; sd[w][4 * lane + 1] = a1;
        sd[w][4 * lane + 2] = a2; sd[w][4 * lane + 3] = a3;
    }
    __syncthreads();

    {   // phase 2: tail per t (all 256 threads)
        double s2 = (sd[0][tid] + sd[1][tid]) + (sd[2][tid] + sd[3][tid]);

        double w2 = 5.2 + s2 * 9.6;
        w2 = fmin(fmax(w2, 0.4), 10.0);
        double iw2 = 1.0 / (w2 * w2);

        const double s = 120.0 / 129.0;
        double G  = exp(-0.125 * s * s * iw2);
        double G2 = G * G, G4 = G2 * G2, G8 = G4 * G4;
        double term = G, cmul = G8, norm = G;
        for (int u = 1; u <= 64; ++u) { term *= cmul; cmul *= G8; norm += term; }
        norm *= 2.0;

        double P = exp(-0.5 * iw2), P2 = P * P;
        double a = 1.0, bm = P, inv = 1.0 / norm;
        double* kr = kernG + (size_t)b * TTT + t0 + tid;   // SoA [d][b*T+t]
        kr[0] = inv;
        #pragma unroll
        for (int d = 1; d <= 6; ++d) {
            a *= bm; bm *= P2;
            kr[(size_t)d * BT] = a * inv;
        }
    }
}

// ---------------------------------------------------------------------------
// kf: barrier-free fused conv + LIF scan + spike output, 4 specialized waves.
// wave0 = scan; waves 1,2 = conv halves (14 ch, reg double-buffer, even/odd
// unrolled — no register rotation); wave3 = out-writer. LDS-only fences.
// ---------------------------------------------------------------------------
#define CONV_BODY(K, XC, KC, XN, KN)                                       \
    {                                                                      \
        const int k_ = (K);                                                \
        if (k_ + 1 < NT) {                                                 \
            const int gt = (k_ + 1) * TPB + lane;                          \
            _Pragma("unroll")                                              \
            for (int i = 0; i < 26; ++i) {                                 \
                int cr = crow0 + i;                                        \
                XN[i] = (cr >= 0 && cr < CCH)                              \
                    ? xbase[((size_t)cr << 11) + gt] : 0.0f;               \
            }                                                              \
            _Pragma("unroll")                                              \
            for (int d = 0; d < 7; ++d)                                    \
                KN[d] = kbase[(size_t)d * BT + gt];                        \
        }                                                                  \
        double iv[14];                                                     \
        _Pragma("unroll")                                                  \
        for (int c = 0; c < 14; ++c) {                                     \
            double acc = 0.0;                                              \
            _Pragma("unroll")                                              \
            for (int kk = 0; kk < 13; ++kk) {                              \
                int d = kk < 6 ? 6 - kk : kk - 6;                          \
                acc = fma((double)XC[c + kk], KC[d], acc);                 \
            }                                                              \
            double xvv = (double)XC[c + 6];                                \
            double dd  = xvv - acc;                                        \
            iv[c] = xvv - (dd > 0.0 ? dd : 0.0);                           \
        }                                                                  \
        const int s_ = k_ & (RD - 1);                                      \
        while (vfl[CF(s_)] < k_ + 1 - RD) {}                               \
        CFENCE();                                                          \
        _Pragma("unroll")                                                  \
        for (int c = 0; c < 14; ++c) Is[s_][lane][cb + c] = iv[c];         \
        if (lane == 0) { LDS_REL(); vfl[PF(h, s_)] = k_ + 1; }             \
    }

__global__ __launch_bounds__(256) void kf(
    const float* __restrict__ x, const double* __restrict__ kernG,
    float* __restrict__ out)
{
    __shared__ double Is[RD][TPB][IROW];                // 59,392 B
    __shared__ unsigned long long bitsb[RD][CG];        //    896 B
    __shared__ int fl[32];
    volatile int* vfl = fl;

    const int b    = blockIdx.y;
    const int c0   = blockIdx.x * CG;
    const int tid  = threadIdx.x;
    const int wid  = tid >> 6;
    const int lane = tid & 63;

    if (tid < 32) fl[tid] = 0;
    __syncthreads();

    const float*  xbase = x + (((size_t)(b * CCH)) << 11);
    const double* kbase = kernG + (size_t)b * TTT;
    float* obase = out + (((size_t)(b * CCH + c0)) << 11);

    if (wid == 1 || wid == 2) {
        // ======================= conv wave (14 ch) =======================
        const int h  = wid - 1;
        const int cb = 14 * h;
        const int crow0 = c0 + cb - 6;
        float  xcA[26], xcB[26];
        double kcA[7],  kcB[7];

        #pragma unroll
        for (int i = 0; i < 26; ++i) {
            int cr = crow0 + i;
            xcA[i] = (cr >= 0 && cr < CCH) ? xbase[((size_t)cr << 11) + lane] : 0.0f;
        }
        #pragma unroll
        for (int d = 0; d < 7; ++d) kcA[d] = kbase[(size_t)d * BT + lane];

        #pragma unroll 1
        for (int k = 0; k < NT; k += 2) {
            CONV_BODY(k,     xcA, kcA, xcB, kcB)
            CONV_BODY(k + 1, xcB, kcB, xcA, kcA)
        }
    } else if (wid == 0) {
        // ========================== scan wave ===========================
        const int c    = lane;
        const int cidx = (c < CG) ? c : 0;
        double mem = 0.0;
        bool   r   = false;

        #pragma unroll 1
        for (int k = 0; k < NT; ++k) {
            const int s = k & (RD - 1);
            while (vfl[PF(0, s)] < k + 1 || vfl[PF(1, s)] < k + 1) {}
            CFENCE();

            unsigned long long bits = 0ull;
            {
                double va[8], vam[8], vb[8], vbm[8];
                #pragma unroll
                for (int j = 0; j < 8; ++j) {
                    va[j] = Is[s][j][cidx]; vam[j] = va[j] - 1.0;
                }
                #pragma unroll
                for (int g = 0; g < 64; g += 16) {
                    #pragma unroll
                    for (int j = 0; j < 8; ++j) {
                        vb[j] = Is[s][g + 8 + j][cidx]; vbm[j] = vb[j] - 1.0;
                    }
                    #pragma unroll
                    for (int j = 0; j < 8; ++j) {
                        double m1 = fma(0.95, mem, va[j]);
                        double m2 = fma(0.95, mem, vam[j]);
                        mem = r ? m2 : m1;
                        r = mem > 1.0;
                        bits |= (unsigned long long)(r ? 1 : 0) << (g + j);
                    }
                    if (g + 16 < 64) {
                        #pragma unroll
                        for (int j = 0; j < 8; ++j) {
                            va[j] = Is[s][g + 16 + j][cidx]; vam[j] = va[j] - 1.0;
                        }
                    }
                    #pragma unroll
                    for (int j = 0; j < 8; ++j) {
                        double m1 = fma(0.95, mem, vb[j]);
                        double m2 = fma(0.95, mem, vbm[j]);
                        mem = r ? m2 : m1;
                        r = mem > 1.0;
                        bits |= (unsigned long long)(r ? 1 : 0) << (g + 8 + j);
                    }
                }
            }
            if (lane == 0) { LDS_REL(); vfl[CF(s)] = k + 1; }

            while (vfl[OW(s)] < k + 1 - RD) {}
            CFENCE();
            if (c < CG) bitsb[s][c] = bits;
            if (lane == 0) { LDS_REL(); vfl[SF(s)] = k + 1; }
        }
    } else {
        // ======================== out-writer wave ========================
        const int qq = lane & 15;            // float4 index within 64 t
        #pragma unroll 1
        for (int k = 0; k < NT; ++k) {
            const int s = k & (RD - 1);
            while (vfl[SF(s)] < k + 1) {}
            CFENCE();
            unsigned long long bb[7];
            #pragma unroll
            for (int i = 0; i < 7; ++i) {
                int cc = (lane >> 4) + 4 * i;          // 0..27
                bb[i] = bitsb[s][cc];
            }
            if (lane == 0) { LDS_REL(); vfl[OW(s)] = k + 1; }
            #pragma unroll
            for (int i = 0; i < 7; ++i) {
                int cc = (lane >> 4) + 4 * i;
                unsigned long long bv = bb[i] >> (4 * qq);
                float4 v;
                v.x = (bv & 1ull) ? 1.0f : 0.0f;
                v.y = (bv & 2ull) ? 1.0f : 0.0f;
                v.z = (bv & 4ull) ? 1.0f : 0.0f;
                v.w = (bv & 8ull) ? 1.0f : 0.0f;
                *(float4*)(obase + ((size_t)cc << 11) + k * TPB + 4 * qq) = v;
            }
        }
    }
}

// ---------------------------------------------------------------------------
extern "C" void kernel_launch(void* const* d_in, const int* in_sizes, int n_in,
                              void* d_out, int out_size, void* d_ws, size_t ws_size,
                              hipStream_t stream)
{
    const float* x  = (const float*)d_in[0];   // (32,1,224,2048) f32
    const float* lw = (const float*)d_in[1];   // (1,224) f32
    float* out = (float*)d_out;                // (32,1,224,2048) f32

    double* kernG = (double*)d_ws;             // SoA 7 * 65536 * 8 = 3,670,016 B

    kw<<<dim3(8, BB), 256, 0, stream>>>(x, lw, kernG);
    kf<<<dim3(NCG, BB), 256, 0, stream>>>(x, kernG, out);
}